// Round 1
// baseline (264.719 us; speedup 1.0000x reference)
//
#include <hip/hip_runtime.h>
#include <math.h>

#define NB 128
#define NT 512
#define NE 128
#define NK 4
#define NNEG 64
#define SCHUNK 32
#define APITCH 33   // float4 pitch for A rows (pad breaks power-of-2 stride)
#define BPITCH 68   // float pitch for B rows (multiple of 4 for b128 alignment)

// LDS: Ash 32*33*16 = 16896 B ; Bsh 128*68*4 = 34816 B ; total 51712 B -> 3 blocks/CU

__global__ void zero_out_k(float* out) { *out = 0.f; }

__launch_bounds__(256, 3)
__global__ void cpc_kernel(const float* __restrict__ base,        // (B,T,E)
                           const float* __restrict__ mce,         // (B,T,E,K)
                           const int*  __restrict__ seq_lens,     // (B)
                           const int*  __restrict__ sample_ids,   // (B,NNEG)
                           float* __restrict__ out)
{
    const int b  = blockIdx.y;
    const int s0 = blockIdx.x * SCHUNK;
    const int L  = seq_lens[b];
    const float LOG65 = 4.1743873f;
    const float wgt[4] = {1.f/261632.f, 1.f/261120.f, 1.f/260608.f, 1.f/260096.f};

    // Fully-masked chunk: every (s,i) with s < T-i contributes ln(65) analytically.
    if (s0 >= L) {
        if (threadIdx.x == 0) {
            float c = 0.f;
            #pragma unroll
            for (int i = 1; i <= NK; ++i) {
                int hi = min(SCHUNK, (NT - i) - s0);
                if (hi > 0) c += (float)hi * LOG65 * wgt[i - 1];
            }
            atomicAdd(out, c);
        }
        return;
    }

    __shared__ float4 Ash[SCHUNK * APITCH];   // [s_local][e_panel] float4 over k
    __shared__ float  Bsh[NE * BPITCH];       // [e][n] negatives

    const int tid  = threadIdx.x;
    const int wave = tid >> 6;
    const int lane = tid & 63;
    const int mg   = lane >> 4;      // 0..3  (s-pair group)
    const int ng   = lane & 15;      // 0..15 (n-quad group)
    const int half = lane >> 5;      // 0..1  (s-half for pos partials)
    const int el   = lane & 31;      // e-lane within panel for pos partials
    const int sw   = s0 + wave * 8;  // this wave's first s

    const float4* mce4 = (const float4*)mce;  // element (b*NT+s)*NE + e holds k=0..3

    // ---- stage negatives: Bsh[e*BPITCH + n] = base[sample_ids[b,n]*NE + e] ----
    {
        const int e  = tid & 127;
        const int nh = tid >> 7;                 // 0/1
        #pragma unroll 4
        for (int it = 0; it < 32; ++it) {
            int n = it * 2 + nh;
            int r = sample_ids[b * NNEG + n];
            Bsh[e * BPITCH + n] = base[r * NE + e];
        }
    }

    float acc[2][4][4];      // [delta s][k][j]  -> neg logits, n = 4*ng + j
    #pragma unroll
    for (int d = 0; d < 2; ++d)
        #pragma unroll
        for (int k = 0; k < 4; ++k)
            #pragma unroll
            for (int j = 0; j < 4; ++j) acc[d][k][j] = 0.f;

    float pp[4][4];          // pos partials: [j = s within half][k]
    #pragma unroll
    for (int j = 0; j < 4; ++j)
        #pragma unroll
        for (int k = 0; k < 4; ++k) pp[j][k] = 0.f;

    // ---- panel loop over e in 4 slabs of 32 ----
    for (int ep = 0; ep < 4; ++ep) {
        if (ep) __syncthreads();                  // previous panel fully consumed
        // stage A panel: 32 s x 32 e float4
        {
            const int e_l = tid & 31;
            const int sl0 = tid >> 5;             // 0..7
            #pragma unroll
            for (int r = 0; r < 4; ++r) {
                int sl = sl0 + 8 * r;
                Ash[sl * APITCH + e_l] =
                    mce4[(b * NT + s0 + sl) * NE + ep * 32 + e_l];
            }
        }
        __syncthreads();                          // also covers Bsh on ep==0

        // GEMM: rows (2 s x 4 k) x cols (4 n), depth 32 e
        {
            const float4* Arow0 = &Ash[(wave * 8 + 2 * mg    ) * APITCH];
            const float4* Arow1 = &Ash[(wave * 8 + 2 * mg + 1) * APITCH];
            const float*  Bcol  = &Bsh[ep * 32 * BPITCH + 4 * ng];
            #pragma unroll 4
            for (int e = 0; e < 32; ++e) {
                float4 a0 = Arow0[e];
                float4 a1 = Arow1[e];
                float4 bv = *(const float4*)(Bcol + e * BPITCH);
                const float* a0f = reinterpret_cast<const float*>(&a0);
                const float* a1f = reinterpret_cast<const float*>(&a1);
                const float* bvf = reinterpret_cast<const float*>(&bv);
                #pragma unroll
                for (int k = 0; k < 4; ++k) {
                    float v0 = a0f[k], v1 = a1f[k];
                    #pragma unroll
                    for (int j = 0; j < 4; ++j) {
                        acc[0][k][j] = fmaf(v0, bvf[j], acc[0][k][j]);
                        acc[1][k][j] = fmaf(v1, bvf[j], acc[1][k][j]);
                    }
                }
            }
        }

        // positive partials for this e-slab (lanes split: half h covers 4 s, 32 e)
        {
            const int eg = ep * 32 + el;
            #pragma unroll
            for (int j = 0; j < 4; ++j) {
                int srow = wave * 8 + 4 * half + j;       // block-local s
                int sg   = s0 + srow;
                float4 av = Ash[srow * APITCH + el];
                const float* af = reinterpret_cast<const float*>(&av);
                #pragma unroll
                for (int i = 1; i <= 4; ++i) {
                    int row = min(sg + i, NT - 1);        // clamped; weight=0 kills it
                    float bb = base[(b * NT + row) * NE + eg];
                    pp[j][i - 1] = fmaf(af[i - 1], bb, pp[j][i - 1]);
                }
            }
        }
    }

    // reduce pos partials over the 32-lane half (e dimension)
    #pragma unroll
    for (int j = 0; j < 4; ++j)
        #pragma unroll
        for (int k = 0; k < 4; ++k) {
            float v = pp[j][k];
            v += __shfl_xor(v, 1);
            v += __shfl_xor(v, 2);
            v += __shfl_xor(v, 4);
            v += __shfl_xor(v, 8);
            v += __shfl_xor(v, 16);
            pp[j][k] = v;     // uniform within half; = pos(s = sw+4*half+j, i=k+1)
        }

    // epilogue: log-sum-exp over 65 logits per (s, i)
    float lossacc = 0.f;
    #pragma unroll
    for (int d = 0; d < 2; ++d) {
        int s = sw + 2 * mg + d;
        bool unm = (s < L);
        int jj = 2 * (mg & 1) + d;                // its half's local s index
        #pragma unroll
        for (int k = 0; k < 4; ++k) {
            if (s < NT - (k + 1)) {               // valid (s,i); uniform per 16-lane group
                float p  = pp[jj][k];
                float z0 = acc[d][k][0], z1 = acc[d][k][1];
                float z2 = acc[d][k][2], z3 = acc[d][k][3];
                float m = fmaxf(fmaxf(z0, z1), fmaxf(z2, z3));
                m = fmaxf(m, __shfl_xor(m, 1));
                m = fmaxf(m, __shfl_xor(m, 2));
                m = fmaxf(m, __shfl_xor(m, 4));
                m = fmaxf(m, __shfl_xor(m, 8));
                m = fmaxf(m, p);
                float ssum = __expf(z0 - m) + __expf(z1 - m)
                           + __expf(z2 - m) + __expf(z3 - m);
                ssum += __shfl_xor(ssum, 1);
                ssum += __shfl_xor(ssum, 2);
                ssum += __shfl_xor(ssum, 4);
                ssum += __shfl_xor(ssum, 8);
                ssum += __expf(p - m);
                float loss = __logf(ssum) + (m - p);
                loss = unm ? loss : LOG65;        // masked position => ln(65)
                lossacc += wgt[k] * loss;
            }
        }
    }
    // lossacc uniform within each 16-lane group; fold groups, one atomic per wave
    lossacc += __shfl_xor(lossacc, 16);
    lossacc += __shfl_xor(lossacc, 32);
    if (lane == 0) atomicAdd(out, lossacc);
}

extern "C" void kernel_launch(void* const* d_in, const int* in_sizes, int n_in,
                              void* d_out, int out_size, void* d_ws, size_t ws_size,
                              hipStream_t stream) {
    (void)in_sizes; (void)n_in; (void)out_size; (void)d_ws; (void)ws_size;
    const float* base       = (const float*)d_in[0];
    const float* mce        = (const float*)d_in[1];
    const int*   seq_lens   = (const int*)d_in[2];
    const int*   sample_ids = (const int*)d_in[3];
    float* out = (float*)d_out;

    zero_out_k<<<1, 1, 0, stream>>>(out);    // d_out is poisoned before timed runs
    dim3 grid(NT / SCHUNK, NB);
    cpc_kernel<<<grid, 256, 0, stream>>>(base, mce, seq_lens, sample_ids, out);
}

// Round 2
// 251.322 us; speedup vs baseline: 1.0533x; 1.0533x over previous
//
#include <hip/hip_runtime.h>
#include <math.h>

#define NB 128
#define NT 512
#define NEDIM 128
#define NNEG 64
#define SCHUNK 32

typedef __bf16 bf16x8 __attribute__((ext_vector_type(8)));
typedef float  f32x4  __attribute__((ext_vector_type(4)));

__global__ void zero_out_k(float* out) { *out = 0.f; }

// M = 128 rows: m = 4*s_local + (i-1).  N = 64 negatives.  K = 128 (e).
// A staged in LDS as fragment-linear 16B chunks (xor-swizzled), bf16.
// B (gathered negatives) staged fragment-linear, bf16.
// LDS: Afrag 32KB + Bfrag 16KB + pos 512B = 49.7KB -> 3 blocks/CU.
__launch_bounds__(256, 3)
__global__ void cpc_mfma_kernel(const float* __restrict__ base,        // (B,T,E)
                                const float* __restrict__ mce,         // (B,T,E,K)
                                const int*  __restrict__ seq_lens,     // (B)
                                const int*  __restrict__ sample_ids,   // (B,NNEG)
                                float* __restrict__ out)
{
    const int b  = blockIdx.y;
    const int s0 = blockIdx.x * SCHUNK;
    const int L  = seq_lens[b];
    const float LOG65 = 4.1743873f;
    const float wgt[4] = {1.f/261632.f, 1.f/261120.f, 1.f/260608.f, 1.f/260096.f};

    // Fully-masked chunk: all-zero ce rows give loss = ln(65) analytically.
    if (s0 >= L) {
        if (threadIdx.x == 0) {
            float c = 0.f;
            #pragma unroll
            for (int i = 1; i <= 4; ++i) {
                int hi = min(SCHUNK, (NT - i) - s0);
                if (hi > 0) c += (float)hi * LOG65 * wgt[i - 1];
            }
            atomicAdd(out, c);
        }
        return;
    }

    __shared__ __bf16 Afrag[2048 * 8];   // 2048 chunks x 16B
    __shared__ __bf16 Bfrag[1024 * 8];   // 1024 chunks x 16B
    __shared__ float  pos_lds[128];

    const int tid  = threadIdx.x;
    const int lane = tid & 63;
    const int w    = tid >> 6;
    const int q    = lane >> 4;
    const int fl   = lane & 15;

    const float4* mce4 = (const float4*)mce;   // (b*NT+s)*NEDIM + e -> 4 k values

    // ---- stage A: transpose k->row, f32->bf16, fragment-linear chunks ----
    // chunk id = (kstep*8 + mt)*64 + q*16 + flm ; phys = chunk ^ ((chunk>>6)&7)
    #pragma unroll
    for (int it = 0; it < 2; ++it) {
        int g  = tid + 256 * it;          // 0..511 : (s, e-block)
        int s  = g & 31;
        int eb = g >> 5;                  // e0 = eb*8
        const float4* src = mce4 + (size_t)(b * NT + s0 + s) * NEDIM + eb * 8;
        float4 v[8];
        #pragma unroll
        for (int u = 0; u < 8; ++u) v[u] = src[u];
        const float* vf = (const float*)v;
        int Cs = (eb >> 2) * 8 + (s >> 2);
        int base_chunk = Cs * 64 + (eb & 3) * 16 + (s & 3) * 4;
        int x = Cs & 7;
        #pragma unroll
        for (int k = 0; k < 4; ++k) {
            int phys = (base_chunk + k) ^ x;
            bf16x8 o;
            #pragma unroll
            for (int u = 0; u < 8; ++u) o[u] = (__bf16)vf[4 * u + k];
            *(bf16x8*)(&Afrag[phys * 8]) = o;
        }
    }

    // ---- stage B: gather negative rows, bf16, fragment-linear (no swizzle) ----
    {
        int n = tid & 63;
        int r = sample_ids[b * NNEG + n];
        const float4* srcb = (const float4*)(base + (size_t)r * NEDIM);
        int eb0 = (tid >> 6) * 4;
        #pragma unroll
        for (int it = 0; it < 4; ++it) {
            int eb = eb0 + it;
            float4 v0 = srcb[eb * 2], v1 = srcb[eb * 2 + 1];
            const float* f0 = (const float*)&v0;
            const float* f1 = (const float*)&v1;
            bf16x8 o;
            #pragma unroll
            for (int u = 0; u < 4; ++u) { o[u] = (__bf16)f0[u]; o[4 + u] = (__bf16)f1[u]; }
            *(bf16x8*)(&Bfrag[(eb * 64 + n) * 8]) = o;
        }
    }
    __syncthreads();

    // ---- MFMA: wave w owns M-tiles {2w,2w+1} x all 4 N-tiles ----
    f32x4 acc[2][4];
    #pragma unroll
    for (int mtl = 0; mtl < 2; ++mtl)
        #pragma unroll
        for (int nt = 0; nt < 4; ++nt) acc[mtl][nt] = (f32x4){0.f, 0.f, 0.f, 0.f};

    #pragma unroll
    for (int kstep = 0; kstep < 4; ++kstep) {
        bf16x8 af[2];
        #pragma unroll
        for (int mtl = 0; mtl < 2; ++mtl) {
            int Cs = kstep * 8 + (2 * w + mtl);
            int phys = (Cs * 64 + lane) ^ (Cs & 7);
            af[mtl] = *(const bf16x8*)(&Afrag[phys * 8]);
        }
        bf16x8 bv[4];
        #pragma unroll
        for (int nt = 0; nt < 4; ++nt) {
            int cB = (kstep * 4 + q) * 64 + nt * 16 + fl;
            bv[nt] = *(const bf16x8*)(&Bfrag[cB * 8]);
        }
        #pragma unroll
        for (int mtl = 0; mtl < 2; ++mtl)
            #pragma unroll
            for (int nt = 0; nt < 4; ++nt)
                acc[mtl][nt] = __builtin_amdgcn_mfma_f32_16x16x32_bf16(
                    af[mtl], bv[nt], acc[mtl][nt], 0, 0, 0);
    }

    // ---- positives: pos[m] = sum_e A[m][e] * base[b][s0+s+i][e] ----
    {
        int m    = tid >> 1;
        int eh   = tid & 1;              // e-half
        int sloc = m >> 2, ip = (m & 3) + 1;
        int srow = s0 + sloc + ip; if (srow > NT - 1) srow = NT - 1;  // clamp; invalid rows excluded later
        const float* brow = base + (size_t)(b * NT + srow) * NEDIM + eh * 64;
        int mt = m >> 4, flm = m & 15;
        float psum = 0.f;
        #pragma unroll
        for (int el = 0; el < 8; ++el) {
            int eb = eh * 8 + el;
            int Cs = (eb >> 2) * 8 + mt;
            int phys = (Cs * 64 + (eb & 3) * 16 + flm) ^ (Cs & 7);
            bf16x8 av = *(const bf16x8*)(&Afrag[phys * 8]);
            #pragma unroll
            for (int u = 0; u < 8; ++u)
                psum = fmaf((float)av[u], brow[el * 8 + u], psum);
        }
        psum += __shfl_xor(psum, 1);
        if (eh == 0) pos_lds[m] = psum;
    }
    __syncthreads();

    // ---- epilogue: logsumexp over 65 logits per row, masked mean ----
    float lossacc = 0.f;
    #pragma unroll
    for (int mtl = 0; mtl < 2; ++mtl) {
        #pragma unroll
        for (int r = 0; r < 4; ++r) {
            int m  = w * 32 + mtl * 16 + q * 4 + r;    // C layout: row=(lane>>4)*4+reg
            int sg = s0 + (m >> 2);
            int ip = (m & 3) + 1;
            float z0 = acc[mtl][0][r], z1 = acc[mtl][1][r];
            float z2 = acc[mtl][2][r], z3 = acc[mtl][3][r];
            float p  = pos_lds[m];
            float mx = fmaxf(fmaxf(z0, z1), fmaxf(z2, z3));
            mx = fmaxf(mx, __shfl_xor(mx, 1));
            mx = fmaxf(mx, __shfl_xor(mx, 2));
            mx = fmaxf(mx, __shfl_xor(mx, 4));
            mx = fmaxf(mx, __shfl_xor(mx, 8));
            mx = fmaxf(mx, p);
            float es = __expf(z0 - mx) + __expf(z1 - mx)
                     + __expf(z2 - mx) + __expf(z3 - mx);
            es += __shfl_xor(es, 1);
            es += __shfl_xor(es, 2);
            es += __shfl_xor(es, 4);
            es += __shfl_xor(es, 8);
            es += __expf(p - mx);
            float loss = __logf(es) + (mx - p);
            loss = (sg < L) ? loss : LOG65;            // masked row => ln(65)
            bool take = (sg < NT - ip) && (fl == 0);   // valid (s,i); one lane per row
            lossacc += take ? wgt[ip - 1] * loss : 0.f;
        }
    }
    lossacc += __shfl_xor(lossacc, 16);
    lossacc += __shfl_xor(lossacc, 32);
    if (lane == 0) atomicAdd(out, lossacc);
}

extern "C" void kernel_launch(void* const* d_in, const int* in_sizes, int n_in,
                              void* d_out, int out_size, void* d_ws, size_t ws_size,
                              hipStream_t stream) {
    (void)in_sizes; (void)n_in; (void)out_size; (void)d_ws; (void)ws_size;
    const float* base       = (const float*)d_in[0];
    const float* mce        = (const float*)d_in[1];
    const int*   seq_lens   = (const int*)d_in[2];
    const int*   sample_ids = (const int*)d_in[3];
    float* out = (float*)d_out;

    zero_out_k<<<1, 1, 0, stream>>>(out);
    dim3 grid(NT / SCHUNK, NB);
    cpc_mfma_kernel<<<grid, 256, 0, stream>>>(base, mce, seq_lens, sample_ids, out);
}

// Round 3
// 224.052 us; speedup vs baseline: 1.1815x; 1.1217x over previous
//
#include <hip/hip_runtime.h>
#include <math.h>

#define NB 128
#define NT 512
#define NEDIM 128
#define NNEG 64
#define SCHUNK 32
#define NBLK (NB * (NT / SCHUNK))   // 2048 partial-sum slots

typedef __bf16 bf16x8 __attribute__((ext_vector_type(8)));
typedef float  f32x4  __attribute__((ext_vector_type(4)));

// M = 128 rows: m = 4*s_local + (i-1).  N = 64 negatives.  K = 128 (e).
// A staged in LDS as fragment-linear 16B chunks (xor-swizzled), bf16.
// B (gathered negatives) staged fragment-linear, bf16.
// Each block writes ONE partial to ws[] — no same-address atomics
// (R2 post-mortem: ~5K device-scope atomicAdds to one dword = ~90 us).
__launch_bounds__(256, 3)
__global__ void cpc_mfma_kernel(const float* __restrict__ base,        // (B,T,E)
                                const float* __restrict__ mce,         // (B,T,E,K)
                                const int*  __restrict__ seq_lens,     // (B)
                                const int*  __restrict__ sample_ids,   // (B,NNEG)
                                float* __restrict__ ws)                // (NBLK)
{
    const int b    = blockIdx.y;
    const int s0   = blockIdx.x * SCHUNK;
    const int slot = b * (NT / SCHUNK) + blockIdx.x;
    const int L    = seq_lens[b];
    const float LOG65 = 4.1743873f;
    const float wgt[4] = {1.f/261632.f, 1.f/261120.f, 1.f/260608.f, 1.f/260096.f};

    // Fully-masked chunk: all-zero ce rows give loss = ln(65) analytically.
    if (s0 >= L) {
        if (threadIdx.x == 0) {
            float c = 0.f;
            #pragma unroll
            for (int i = 1; i <= 4; ++i) {
                int hi = min(SCHUNK, (NT - i) - s0);
                if (hi > 0) c += (float)hi * LOG65 * wgt[i - 1];
            }
            ws[slot] = c;
        }
        return;
    }

    __shared__ __bf16 Afrag[2048 * 8];   // 2048 chunks x 16B
    __shared__ __bf16 Bfrag[1024 * 8];   // 1024 chunks x 16B
    __shared__ float  pos_lds[128];
    __shared__ float  wsum[4];

    const int tid  = threadIdx.x;
    const int lane = tid & 63;
    const int w    = tid >> 6;
    const int q    = lane >> 4;
    const int fl   = lane & 15;

    const float4* mce4 = (const float4*)mce;   // (b*NT+s)*NEDIM + e -> 4 k values

    // ---- stage A: transpose k->row, f32->bf16, fragment-linear chunks ----
    // chunk id = (kstep*8 + mt)*64 + q*16 + flm ; phys = chunk ^ ((chunk>>6)&7)
    #pragma unroll
    for (int it = 0; it < 2; ++it) {
        int g  = tid + 256 * it;          // 0..511 : (s, e-block)
        int s  = g & 31;
        int eb = g >> 5;                  // e0 = eb*8
        const float4* src = mce4 + (size_t)(b * NT + s0 + s) * NEDIM + eb * 8;
        float4 v[8];
        #pragma unroll
        for (int u = 0; u < 8; ++u) v[u] = src[u];
        const float* vf = (const float*)v;
        int Cs = (eb >> 2) * 8 + (s >> 2);
        int base_chunk = Cs * 64 + (eb & 3) * 16 + (s & 3) * 4;
        int x = Cs & 7;
        #pragma unroll
        for (int k = 0; k < 4; ++k) {
            int phys = (base_chunk + k) ^ x;
            bf16x8 o;
            #pragma unroll
            for (int u = 0; u < 8; ++u) o[u] = (__bf16)vf[4 * u + k];
            *(bf16x8*)(&Afrag[phys * 8]) = o;
        }
    }

    // ---- stage B: gather negative rows, bf16, fragment-linear (no swizzle) ----
    {
        int n = tid & 63;
        int r = sample_ids[b * NNEG + n];
        const float4* srcb = (const float4*)(base + (size_t)r * NEDIM);
        int eb0 = (tid >> 6) * 4;
        #pragma unroll
        for (int it = 0; it < 4; ++it) {
            int eb = eb0 + it;
            float4 v0 = srcb[eb * 2], v1 = srcb[eb * 2 + 1];
            const float* f0 = (const float*)&v0;
            const float* f1 = (const float*)&v1;
            bf16x8 o;
            #pragma unroll
            for (int u = 0; u < 4; ++u) { o[u] = (__bf16)f0[u]; o[4 + u] = (__bf16)f1[u]; }
            *(bf16x8*)(&Bfrag[(eb * 64 + n) * 8]) = o;
        }
    }
    __syncthreads();

    // ---- MFMA: wave w owns M-tiles {2w,2w+1} x all 4 N-tiles ----
    f32x4 acc[2][4];
    #pragma unroll
    for (int mtl = 0; mtl < 2; ++mtl)
        #pragma unroll
        for (int nt = 0; nt < 4; ++nt) acc[mtl][nt] = (f32x4){0.f, 0.f, 0.f, 0.f};

    #pragma unroll
    for (int kstep = 0; kstep < 4; ++kstep) {
        bf16x8 af[2];
        #pragma unroll
        for (int mtl = 0; mtl < 2; ++mtl) {
            int Cs = kstep * 8 + (2 * w + mtl);
            int phys = (Cs * 64 + lane) ^ (Cs & 7);
            af[mtl] = *(const bf16x8*)(&Afrag[phys * 8]);
        }
        bf16x8 bv[4];
        #pragma unroll
        for (int nt = 0; nt < 4; ++nt) {
            int cB = (kstep * 4 + q) * 64 + nt * 16 + fl;
            bv[nt] = *(const bf16x8*)(&Bfrag[cB * 8]);
        }
        #pragma unroll
        for (int mtl = 0; mtl < 2; ++mtl)
            #pragma unroll
            for (int nt = 0; nt < 4; ++nt)
                acc[mtl][nt] = __builtin_amdgcn_mfma_f32_16x16x32_bf16(
                    af[mtl], bv[nt], acc[mtl][nt], 0, 0, 0);
    }

    // ---- positives: pos[m] = sum_e A[m][e] * base[b][s0+s+i][e] ----
    {
        int m    = tid >> 1;
        int eh   = tid & 1;              // e-half
        int sloc = m >> 2, ip = (m & 3) + 1;
        int srow = s0 + sloc + ip; if (srow > NT - 1) srow = NT - 1;  // clamp; invalid rows excluded later
        const float4* brow4 = (const float4*)(base + (size_t)(b * NT + srow) * NEDIM + eh * 64);
        int mt = m >> 4, flm = m & 15;
        float psum = 0.f;
        #pragma unroll
        for (int el = 0; el < 8; ++el) {
            int eb = eh * 8 + el;
            int Cs = (eb >> 2) * 8 + mt;
            int phys = (Cs * 64 + (eb & 3) * 16 + flm) ^ (Cs & 7);
            bf16x8 av = *(const bf16x8*)(&Afrag[phys * 8]);
            float4 b0 = brow4[el * 2], b1 = brow4[el * 2 + 1];
            const float* f0 = (const float*)&b0;
            const float* f1 = (const float*)&b1;
            #pragma unroll
            for (int u = 0; u < 4; ++u) {
                psum = fmaf((float)av[u],     f0[u], psum);
                psum = fmaf((float)av[4 + u], f1[u], psum);
            }
        }
        psum += __shfl_xor(psum, 1);
        if (eh == 0) pos_lds[m] = psum;
    }
    __syncthreads();

    // ---- epilogue: logsumexp over 65 logits per row, masked mean ----
    float lossacc = 0.f;
    #pragma unroll
    for (int mtl = 0; mtl < 2; ++mtl) {
        #pragma unroll
        for (int r = 0; r < 4; ++r) {
            int m  = w * 32 + mtl * 16 + q * 4 + r;    // C layout: row=(lane>>4)*4+reg
            int sg = s0 + (m >> 2);
            int ip = (m & 3) + 1;
            float z0 = acc[mtl][0][r], z1 = acc[mtl][1][r];
            float z2 = acc[mtl][2][r], z3 = acc[mtl][3][r];
            float p  = pos_lds[m];
            float mx = fmaxf(fmaxf(z0, z1), fmaxf(z2, z3));
            mx = fmaxf(mx, __shfl_xor(mx, 1));
            mx = fmaxf(mx, __shfl_xor(mx, 2));
            mx = fmaxf(mx, __shfl_xor(mx, 4));
            mx = fmaxf(mx, __shfl_xor(mx, 8));
            mx = fmaxf(mx, p);
            float es = __expf(z0 - mx) + __expf(z1 - mx)
                     + __expf(z2 - mx) + __expf(z3 - mx);
            es += __shfl_xor(es, 1);
            es += __shfl_xor(es, 2);
            es += __shfl_xor(es, 4);
            es += __shfl_xor(es, 8);
            es += __expf(p - mx);
            float loss = __logf(es) + (mx - p);
            loss = (sg < L) ? loss : LOG65;            // masked row => ln(65)
            bool take = (sg < NT - ip) && (fl == 0);   // valid (s,i); one lane per row
            lossacc += take ? wgt[ip - 1] * loss : 0.f;
        }
    }
    lossacc += __shfl_xor(lossacc, 16);
    lossacc += __shfl_xor(lossacc, 32);
    if (lane == 0) wsum[w] = lossacc;
    __syncthreads();
    if (tid == 0) ws[slot] = wsum[0] + wsum[1] + wsum[2] + wsum[3];
}

// Sum the 2048 per-block partials -> out[0]. One block, no atomics.
__global__ void reduce_k(const float* __restrict__ ws, float* __restrict__ out) {
    const int tid = threadIdx.x;   // 256
    float s = 0.f;
    #pragma unroll
    for (int i = 0; i < NBLK / 256; ++i) s += ws[tid + 256 * i];
    s += __shfl_xor(s, 1);
    s += __shfl_xor(s, 2);
    s += __shfl_xor(s, 4);
    s += __shfl_xor(s, 8);
    s += __shfl_xor(s, 16);
    s += __shfl_xor(s, 32);
    __shared__ float wsum[4];
    if ((tid & 63) == 0) wsum[tid >> 6] = s;
    __syncthreads();
    if (tid == 0) out[0] = wsum[0] + wsum[1] + wsum[2] + wsum[3];
}

extern "C" void kernel_launch(void* const* d_in, const int* in_sizes, int n_in,
                              void* d_out, int out_size, void* d_ws, size_t ws_size,
                              hipStream_t stream) {
    (void)in_sizes; (void)n_in; (void)out_size; (void)ws_size;
    const float* base       = (const float*)d_in[0];
    const float* mce        = (const float*)d_in[1];
    const int*   seq_lens   = (const int*)d_in[2];
    const int*   sample_ids = (const int*)d_in[3];
    float* out = (float*)d_out;
    float* ws  = (float*)d_ws;   // 2048 floats; every block writes its slot

    dim3 grid(NT / SCHUNK, NB);
    cpc_mfma_kernel<<<grid, 256, 0, stream>>>(base, mce, seq_lens, sample_ids, ws);
    reduce_k<<<1, 256, 0, stream>>>(ws, out);
}